// Round 1
// baseline (464.796 us; speedup 1.0000x reference)
//
#include <hip/hip_runtime.h>

// Problem constants
#define BB 256      // batch
#define VV 50257    // per-model vocab
#define UU 65536    // union vocab
#define MM 3        // models
#define NT 1024     // u-tiles (UU / 64)

typedef float float4a __attribute__((ext_vector_type(4), aligned(4)));
typedef _Float16 half4 __attribute__((ext_vector_type(4)));

// ---------------------------------------------------------------------------
// FAST-PATH workspace layout (bytes):
//   0      : Z      [3*256] float  (softmax denominators; memset 0 each call)
//   3072   : hist   [1024]  int    (memset 0 each call)
//   7168   : off    [1025]  int
//   11296  : cursor [1024]  int
//   15392  : sorted [150771] int   (packed (j<<8)|(m<<6)|(u&63))
//   618496 : ET     [3][50257][256] fp16  (77,194,752 B)
// total 77,813,248 B  (identical to previous round)
// ---------------------------------------------------------------------------
#define WS_Z      0
#define WS_HIST   3072
#define WS_OFF    7168
#define WS_CURSOR 11296
#define WS_SORTED 15392
#define WS_ET     618496
#define WS_NEED   77813248ull

// ---------------------------------------------------------------------------
// winv[m*B+b] = w_m / sum_j exp(logits[m][b][j]).  FALLBACK PATH ONLY.
// ---------------------------------------------------------------------------
__global__ __launch_bounds__(512) void row_sums_kernel(
    const float* __restrict__ l0, const float* __restrict__ l1,
    const float* __restrict__ l2, const float* __restrict__ weights,
    float* __restrict__ winv)
{
    const int bx = blockIdx.x;            // [0, MM*BB)
    const int m  = bx >> 8;
    const int b  = bx & 255;
    const float* lg  = (m == 0) ? l0 : (m == 1) ? l1 : l2;
    const float* row = lg + (size_t)b * VV;
    const float4a* rowv = (const float4a*)row;

    const int nv4 = VV / 4;               // 12564, tail element j=50256
    float partial = 0.0f;
    for (int i = threadIdx.x; i < nv4; i += 512) {
        float4a v = rowv[i];
        partial += __expf(v.x) + __expf(v.y) + __expf(v.z) + __expf(v.w);
    }
    if (threadIdx.x == 0) partial += __expf(row[VV - 1]);

    #pragma unroll
    for (int off = 32; off > 0; off >>= 1)
        partial += __shfl_down(partial, off, 64);

    __shared__ float smem[8];
    const int lane = threadIdx.x & 63;
    const int wv   = threadIdx.x >> 6;
    if (lane == 0) smem[wv] = partial;
    __syncthreads();
    if (threadIdx.x == 0) {
        float tot = 0.0f;
        #pragma unroll
        for (int w = 0; w < 8; ++w) tot += smem[w];
        winv[bx] = weights[m] / tot;
    }
}

// ---------------------------------------------------------------------------
// u-tile histogram over all 3 maps.  64 blocks x 1024, LDS-aggregated.
// ---------------------------------------------------------------------------
__global__ __launch_bounds__(1024) void hist_count_kernel(
    const int* __restrict__ m0, const int* __restrict__ m1,
    const int* __restrict__ m2, int* __restrict__ hist)
{
    __shared__ int h[NT];
    for (int i = threadIdx.x; i < NT; i += 1024) h[i] = 0;
    __syncthreads();
    const int total = MM * VV;
    for (int idx = blockIdx.x * 1024 + threadIdx.x; idx < total;
         idx += gridDim.x * 1024) {
        const int m = idx / VV;           // const divisor -> magic mul
        const int j = idx - m * VV;
        const int* mp = (m == 0) ? m0 : (m == 1) ? m1 : m2;
        atomicAdd(&h[mp[j] >> 6], 1);
    }
    __syncthreads();
    for (int i = threadIdx.x; i < NT; i += 1024) atomicAdd(&hist[i], h[i]);
}

// ---------------------------------------------------------------------------
// Single-block exclusive scan over 1024 bins (Hillis-Steele in LDS).
// ---------------------------------------------------------------------------
__global__ __launch_bounds__(1024) void prefix_kernel(
    const int* __restrict__ hist, int* __restrict__ off, int* __restrict__ cursor)
{
    __shared__ int s[NT];
    const int t = threadIdx.x;
    const int mine = hist[t];
    s[t] = mine;
    __syncthreads();
    for (int d = 1; d < NT; d <<= 1) {
        int v = (t >= d) ? s[t - d] : 0;
        __syncthreads();
        s[t] += v;
        __syncthreads();
    }
    const int excl = s[t] - mine;
    off[t] = excl;
    cursor[t] = excl;
    if (t == NT - 1) off[NT] = s[t];
}

// ---------------------------------------------------------------------------
// Scatter (m,j,u) entries into u-tile-sorted order.
// ---------------------------------------------------------------------------
__global__ __launch_bounds__(256) void sort_kernel(
    const int* __restrict__ m0, const int* __restrict__ m1,
    const int* __restrict__ m2, int* __restrict__ cursor,
    int* __restrict__ sorted)
{
    const int total = MM * VV;
    for (int idx = blockIdx.x * 256 + threadIdx.x; idx < total;
         idx += gridDim.x * 256) {
        const int m = idx / VV;
        const int j = idx - m * VV;
        const int* mp = (m == 0) ? m0 : (m == 1) ? m1 : m2;
        const int u = mp[j];
        const int pos = atomicAdd(&cursor[u >> 6], 1);
        sorted[pos] = (j << 8) | (m << 6) | (u & 63);
    }
}

// ---------------------------------------------------------------------------
// Tiled transpose + exp: ET[m][j][b] = (fp16) exp(logits[m][b][j]).
// 64x64 tile through LDS; both global sides coalesced.
// FUSED: accumulates per-(m,b) row sums of exp into Z (replaces the
// row_sums kernel's full 154 MB logits re-read).
// ---------------------------------------------------------------------------
__global__ __launch_bounds__(256) void transpose_exp_kernel(
    const float* __restrict__ l0, const float* __restrict__ l1,
    const float* __restrict__ l2, _Float16* __restrict__ ET,
    float* __restrict__ Z)
{
    const int m  = blockIdx.z;
    const float* lg = (m == 0) ? l0 : (m == 1) ? l1 : l2;
    const int j0 = blockIdx.x * 64;
    const int b0 = blockIdx.y * 64;
    __shared__ float tile[64][65];
    __shared__ float ps[4][64];
    const int lane = threadIdx.x & 63;
    const int sub  = threadIdx.x >> 6;    // wave id 0..3

    const int j = j0 + lane;
    if (j < VV) {
        #pragma unroll
        for (int rr = 0; rr < 16; ++rr) {
            const int b = b0 + rr * 4 + sub;
            tile[lane][rr * 4 + sub] = __expf(lg[(size_t)b * VV + j]);
        }
    }
    __syncthreads();
    // write phase: thread (sub,lane) owns batch row b = b0+lane for the
    // jj = sub (mod 4) stripe -> accumulate its exp-sum for free.
    float partial = 0.0f;
    #pragma unroll
    for (int rr = 0; rr < 16; ++rr) {
        const int jj = rr * 4 + sub;
        const int jw = j0 + jj;
        if (jw < VV) {
            const float v = tile[jj][lane];
            ET[((size_t)m * VV + jw) * BB + b0 + lane] = (_Float16)v;
            partial += v;
        }
    }
    ps[sub][lane] = partial;
    __syncthreads();
    if (sub == 0)
        atomicAdd(&Z[m * BB + b0 + lane],
                  ps[0][lane] + ps[1][lane] + ps[2][lane] + ps[3][lane]);
}

// ---------------------------------------------------------------------------
// Accumulate v2: block = (64-wide u-tile, 64-wide batch quarter).
//   - LDS accumulator 64x64 f32 = 16 KB -> 8 blocks/CU (was 2 at 64 KB).
//   - 256 threads = 16 entry-subgroups x 16 lanes; each lane loads 4
//     consecutive-b fp16 (8 B vectorized) -> 16 entries in flight/iter.
//   - cross-subgroup ul collisions handled by LDS atomicAdd (ds_add_f32);
//     "+ul" row rotation spreads the 4-aligned addresses across bank
//     residues and makes the drain conflict-free.
//   - winv computed in-block from fused Z (w_m / Z_m[b]).
// Full coverage -> no output memset.
// ---------------------------------------------------------------------------
__global__ __launch_bounds__(256, 8) void accumulate2_kernel(
    const _Float16* __restrict__ ET, const int* __restrict__ sorted,
    const int* __restrict__ off, const float* __restrict__ Z,
    const float* __restrict__ weights, float* __restrict__ out)
{
    const int k  = blockIdx.x;            // u-tile
    const int b0 = blockIdx.y * 64;       // batch quarter
    const int t  = threadIdx.x;

    __shared__ float acc[64 * 64];
    __shared__ float wl[3 * 64];

    for (int i = t; i < 64 * 64; i += 256) acc[i] = 0.0f;
    if (t < 192) {
        const int mm = t >> 6, bl = t & 63;
        wl[t] = weights[mm] / Z[mm * BB + b0 + bl];
    }
    __syncthreads();

    const int g   = t & 15;               // b-group: owns b0+4g..b0+4g+3
    const int sub = t >> 4;               // entry subgroup 0..15
    float4a wv0, wv1, wv2;                // per-thread winv for its 4 b's
    #pragma unroll
    for (int c = 0; c < 4; ++c) {
        wv0[c] = wl[0 * 64 + 4 * g + c];
        wv1[c] = wl[1 * 64 + 4 * g + c];
        wv2[c] = wl[2 * 64 + 4 * g + c];
    }

    const int s = off[k], eEnd = off[k + 1];
    for (int i = s + sub; i < eEnd; i += 16) {
        const int pack = sorted[i];       // broadcast within subgroup
        const int ul = pack & 63;
        const int m  = (pack >> 6) & 3;
        const int j  = pack >> 8;
        const half4 hv =
            *(const half4*)(ET + ((size_t)m * VV + j) * BB + b0 + 4 * g);
        const float4a wm = (m == 0) ? wv0 : (m == 1) ? wv1 : wv2;
        const int rowbase = ul * 64;
        #pragma unroll
        for (int c = 0; c < 4; ++c) {
            const int bl = 4 * g + c;
            atomicAdd(&acc[rowbase + ((bl + ul) & 63)], wm[c] * (float)hv[c]);
        }
    }
    __syncthreads();

    const int lane = t & 63, s4 = t >> 6;
    const int u0 = k * 64;
    #pragma unroll 4
    for (int r = 0; r < 16; ++r) {
        const int bl = r * 4 + s4;
        out[(size_t)(b0 + bl) * UU + u0 + lane] =
            acc[lane * 64 + ((bl + lane) & 63)];
    }
}

// ===========================================================================
// FALLBACK (proven round-2 path) — used only if ws_size < WS_NEED.
// ===========================================================================
#define FB_NBUCK 8
#define FB_BSZ   8192

__global__ __launch_bounds__(256) void fb_count_kernel(
    const int* __restrict__ m0, const int* __restrict__ m1,
    const int* __restrict__ m2, int* __restrict__ cnt)
{
    const int m = blockIdx.y;
    const int* mp = (m == 0) ? m0 : (m == 1) ? m1 : m2;
    __shared__ int hist[FB_NBUCK];
    if (threadIdx.x < FB_NBUCK) hist[threadIdx.x] = 0;
    __syncthreads();
    const int j = blockIdx.x * 256 + threadIdx.x;
    if (j < VV) atomicAdd(&hist[mp[j] >> 13], 1);
    __syncthreads();
    if (threadIdx.x < FB_NBUCK)
        atomicAdd(&cnt[m * FB_NBUCK + threadIdx.x], hist[threadIdx.x]);
}

__global__ void fb_prefix_kernel(const int* __restrict__ cnt,
                                 int* __restrict__ off, int* __restrict__ cursor)
{
    for (int m = 0; m < MM; ++m) {
        int acc = 0;
        for (int k = 0; k < FB_NBUCK; ++k) {
            off[m * (FB_NBUCK + 1) + k] = acc;
            cursor[m * FB_NBUCK + k]    = acc;
            acc += cnt[m * FB_NBUCK + k];
        }
        off[m * (FB_NBUCK + 1) + FB_NBUCK] = acc;
    }
}

__global__ __launch_bounds__(256) void fb_scatter_kernel(
    const int* __restrict__ m0, const int* __restrict__ m1,
    const int* __restrict__ m2, int* __restrict__ cursor,
    int* __restrict__ sorted)
{
    const int m = blockIdx.y;
    const int* mp = (m == 0) ? m0 : (m == 1) ? m1 : m2;
    int* srt = sorted + (size_t)m * VV;
    const int j = blockIdx.x * 256 + threadIdx.x;
    int u = 0, bucket = FB_NBUCK;
    if (j < VV) { u = mp[j]; bucket = u >> 13; }
    const int lane = threadIdx.x & 63;
    const unsigned long long lt = (1ull << lane) - 1ull;
    #pragma unroll
    for (int k = 0; k < FB_NBUCK; ++k) {
        unsigned long long mask = __ballot(bucket == k);
        if (mask) {
            int leader = __ffsll((long long)mask) - 1;
            int base = 0;
            if (lane == leader)
                base = atomicAdd(&cursor[m * FB_NBUCK + k], __popcll(mask));
            base = __shfl(base, leader, 64);
            if (bucket == k) {
                int pos = base + __popcll(mask & lt);
                srt[pos] = ((u & (FB_BSZ - 1)) << 16) | j;
            }
        }
    }
}

__global__ __launch_bounds__(512) void fb_accumulate_kernel(
    const float* __restrict__ l0, const float* __restrict__ l1,
    const float* __restrict__ l2,
    const int* __restrict__ sorted, const int* __restrict__ off,
    const float* __restrict__ winv, float* __restrict__ out)
{
    const int k = blockIdx.x;
    const int b = blockIdx.y;
    __shared__ float acc[FB_BSZ];
    for (int i = threadIdx.x; i < FB_BSZ; i += 512) acc[i] = 0.0f;
    __syncthreads();
    #pragma unroll
    for (int m = 0; m < MM; ++m) {
        const float* lg = (m == 0) ? l0 : (m == 1) ? l1 : l2;
        const float* row = lg + (size_t)b * VV;
        const int* srt = sorted + (size_t)m * VV;
        const float wv = winv[m * BB + b];
        const int s = off[m * (FB_NBUCK + 1) + k];
        const int e = off[m * (FB_NBUCK + 1) + k + 1];
        for (int i = s + threadIdx.x; i < e; i += 512) {
            const int pack = srt[i];
            atomicAdd(&acc[pack >> 16], wv * __expf(row[pack & 0xFFFF]));
        }
    }
    __syncthreads();
    float* orow = out + (size_t)b * UU + (size_t)k * FB_BSZ;
    for (int i = threadIdx.x; i < FB_BSZ; i += 512) orow[i] = acc[i];
}

// ---------------------------------------------------------------------------
extern "C" void kernel_launch(void* const* d_in, const int* in_sizes, int n_in,
                              void* d_out, int out_size, void* d_ws, size_t ws_size,
                              hipStream_t stream)
{
    const float* l0 = (const float*)d_in[0];
    const float* l1 = (const float*)d_in[1];
    const float* l2 = (const float*)d_in[2];
    const int*   m0 = (const int*)d_in[3];
    const int*   m1 = (const int*)d_in[4];
    const int*   m2 = (const int*)d_in[5];
    const float* w  = (const float*)d_in[6];
    float* out = (float*)d_out;
    char* ws = (char*)d_ws;

    if (ws_size >= WS_NEED) {
        float*    Z      = (float*)   (ws + WS_Z);
        int*      hist   = (int*)     (ws + WS_HIST);
        int*      off    = (int*)     (ws + WS_OFF);
        int*      cursor = (int*)     (ws + WS_CURSOR);
        int*      sorted = (int*)     (ws + WS_SORTED);
        _Float16* ET     = (_Float16*)(ws + WS_ET);

        // zero Z (3072 B) + hist (4096 B) in one shot
        hipMemsetAsync(ws, 0, 7168, stream);

        hist_count_kernel<<<64, 1024, 0, stream>>>(m0, m1, m2, hist);
        prefix_kernel<<<1, 1024, 0, stream>>>(hist, off, cursor);
        sort_kernel<<<256, 256, 0, stream>>>(m0, m1, m2, cursor, sorted);

        dim3 gtr((VV + 63) / 64, BB / 64, MM);      // (786, 4, 3)
        transpose_exp_kernel<<<gtr, 256, 0, stream>>>(l0, l1, l2, ET, Z);

        dim3 gacc(NT, BB / 64);                     // (1024, 4)
        accumulate2_kernel<<<gacc, 256, 0, stream>>>(ET, sorted, off, Z, w, out);
    } else {
        // round-2 fallback layout
        float* winv   = (float*)(ws + 0);
        int*   cnt    = (int*)  (ws + 3072);
        int*   off    = (int*)  (ws + 3200);
        int*   cursor = (int*)  (ws + 3456);
        int*   sorted = (int*)  (ws + 3584);

        hipMemsetAsync(cnt, 0, MM * FB_NBUCK * sizeof(int), stream);
        row_sums_kernel<<<MM * BB, 512, 0, stream>>>(l0, l1, l2, w, winv);
        dim3 gmap((VV + 255) / 256, MM);
        fb_count_kernel<<<gmap, 256, 0, stream>>>(m0, m1, m2, cnt);
        fb_prefix_kernel<<<1, 1, 0, stream>>>(cnt, off, cursor);
        fb_scatter_kernel<<<gmap, 256, 0, stream>>>(m0, m1, m2, cursor, sorted);
        dim3 gacc(FB_NBUCK, BB);
        fb_accumulate_kernel<<<gacc, 512, 0, stream>>>(l0, l1, l2, sorted, off, winv, out);
    }
}

// Round 2
// 287.569 us; speedup vs baseline: 1.6163x; 1.6163x over previous
//
#include <hip/hip_runtime.h>

// Problem constants
#define BB 256      // batch
#define VV 50257    // per-model vocab
#define UU 65536    // union vocab
#define MM 3        // models
#define TILE 16     // u-tile width (union slots per accumulate block)
#define NT 4096     // u-tiles (UU / TILE)

typedef float float4a __attribute__((ext_vector_type(4), aligned(4)));

// ---------------------------------------------------------------------------
// FAST-PATH workspace layout (bytes):
//   0      : Z      [3*256] float  (softmax denominators; memset 0 each call)
//   3072   : hist   [4096]  int    (memset 0 each call)
//   19456  : off    [4097]  int
//   35856  : cursor [4096]  int    (16-aligned for int4 stores)
//   52240  : sorted [150771] int   (packed (j<<8)|(m<<6)|(u&15))
//   655360 : ET     [3][50257][256] fp16  (77,194,752 B)
// total 77,850,112 B
// ---------------------------------------------------------------------------
#define WS_Z      0
#define WS_HIST   3072
#define WS_OFF    19456
#define WS_CURSOR 35856
#define WS_SORTED 52240
#define WS_ET     655360
#define WS_NEED   77850112ull

// ---------------------------------------------------------------------------
// winv[m*B+b] = w_m / sum_j exp(logits[m][b][j]).  FALLBACK PATH ONLY.
// ---------------------------------------------------------------------------
__global__ __launch_bounds__(512) void row_sums_kernel(
    const float* __restrict__ l0, const float* __restrict__ l1,
    const float* __restrict__ l2, const float* __restrict__ weights,
    float* __restrict__ winv)
{
    const int bx = blockIdx.x;            // [0, MM*BB)
    const int m  = bx >> 8;
    const int b  = bx & 255;
    const float* lg  = (m == 0) ? l0 : (m == 1) ? l1 : l2;
    const float* row = lg + (size_t)b * VV;
    const float4a* rowv = (const float4a*)row;

    const int nv4 = VV / 4;               // 12564, tail element j=50256
    float partial = 0.0f;
    for (int i = threadIdx.x; i < nv4; i += 512) {
        float4a v = rowv[i];
        partial += __expf(v.x) + __expf(v.y) + __expf(v.z) + __expf(v.w);
    }
    if (threadIdx.x == 0) partial += __expf(row[VV - 1]);

    #pragma unroll
    for (int off = 32; off > 0; off >>= 1)
        partial += __shfl_down(partial, off, 64);

    __shared__ float smem[8];
    const int lane = threadIdx.x & 63;
    const int wv   = threadIdx.x >> 6;
    if (lane == 0) smem[wv] = partial;
    __syncthreads();
    if (threadIdx.x == 0) {
        float tot = 0.0f;
        #pragma unroll
        for (int w = 0; w < 8; ++w) tot += smem[w];
        winv[bx] = weights[m] / tot;
    }
}

// ---------------------------------------------------------------------------
// u-tile histogram over all 3 maps.  Direct global int atomics (native
// ds/global_atomic_add_u32): 150,771 atomics over 4096 bins ~ 37/bin.
// ---------------------------------------------------------------------------
__global__ __launch_bounds__(256) void hist_count_kernel(
    const int* __restrict__ m0, const int* __restrict__ m1,
    const int* __restrict__ m2, int* __restrict__ hist)
{
    const int total = MM * VV;
    for (int idx = blockIdx.x * 256 + threadIdx.x; idx < total;
         idx += gridDim.x * 256) {
        const int m = idx / VV;           // const divisor -> magic mul
        const int j = idx - m * VV;
        const int* mp = (m == 0) ? m0 : (m == 1) ? m1 : m2;
        atomicAdd(&hist[mp[j] >> 4], 1);
    }
}

// ---------------------------------------------------------------------------
// Single-block exclusive scan over 4096 bins: 4 bins/thread serial prefix +
// Hillis-Steele over the 1024 per-thread sums.
// ---------------------------------------------------------------------------
__global__ __launch_bounds__(1024) void prefix_kernel(
    const int* __restrict__ hist, int* __restrict__ off, int* __restrict__ cursor)
{
    __shared__ int s[1024];
    const int t = threadIdx.x;
    const int4 h = ((const int4*)hist)[t];        // bins 4t..4t+3
    const int sum = h.x + h.y + h.z + h.w;
    s[t] = sum;
    __syncthreads();
    for (int d = 1; d < 1024; d <<= 1) {
        int v = (t >= d) ? s[t - d] : 0;
        __syncthreads();
        s[t] += v;
        __syncthreads();
    }
    const int excl = s[t] - sum;
    int4 o;
    o.x = excl;
    o.y = o.x + h.x;
    o.z = o.y + h.y;
    o.w = o.z + h.z;
    ((int4*)off)[t]    = o;
    ((int4*)cursor)[t] = o;
    if (t == 1023) off[NT] = o.w + h.w;
}

// ---------------------------------------------------------------------------
// Scatter (m,j,u) entries into u-tile-sorted order.
// ---------------------------------------------------------------------------
__global__ __launch_bounds__(256) void sort_kernel(
    const int* __restrict__ m0, const int* __restrict__ m1,
    const int* __restrict__ m2, int* __restrict__ cursor,
    int* __restrict__ sorted)
{
    const int total = MM * VV;
    for (int idx = blockIdx.x * 256 + threadIdx.x; idx < total;
         idx += gridDim.x * 256) {
        const int m = idx / VV;
        const int j = idx - m * VV;
        const int* mp = (m == 0) ? m0 : (m == 1) ? m1 : m2;
        const int u = mp[j];
        const int pos = atomicAdd(&cursor[u >> 4], 1);
        sorted[pos] = (j << 8) | (m << 6) | (u & 15);
    }
}

// ---------------------------------------------------------------------------
// Tiled transpose + exp: ET[m][j][b] = (fp16) exp(logits[m][b][j]).
// 64x64 tile through LDS; both global sides coalesced.
// FUSED: accumulates per-(m,b) row sums of exp into Z (saves the 154 MB
// logits re-read a separate row_sums pass would cost).  Z atomics are
// low-contention (786 adds per address spread over the whole kernel).
// ---------------------------------------------------------------------------
__global__ __launch_bounds__(256) void transpose_exp_kernel(
    const float* __restrict__ l0, const float* __restrict__ l1,
    const float* __restrict__ l2, _Float16* __restrict__ ET,
    float* __restrict__ Z)
{
    const int m  = blockIdx.z;
    const float* lg = (m == 0) ? l0 : (m == 1) ? l1 : l2;
    const int j0 = blockIdx.x * 64;
    const int b0 = blockIdx.y * 64;
    __shared__ float tile[64][65];
    __shared__ float ps[4][64];
    const int lane = threadIdx.x & 63;
    const int sub  = threadIdx.x >> 6;    // wave id 0..3

    const int j = j0 + lane;
    if (j < VV) {
        #pragma unroll
        for (int rr = 0; rr < 16; ++rr) {
            const int b = b0 + rr * 4 + sub;
            tile[lane][rr * 4 + sub] = __expf(lg[(size_t)b * VV + j]);
        }
    }
    __syncthreads();
    // write phase: thread (sub,lane) owns batch row b = b0+lane for the
    // jj = sub (mod 4) stripe -> accumulate its exp-sum for free.
    float partial = 0.0f;
    #pragma unroll
    for (int rr = 0; rr < 16; ++rr) {
        const int jj = rr * 4 + sub;
        const int jw = j0 + jj;
        if (jw < VV) {
            const float v = tile[jj][lane];
            ET[((size_t)m * VV + jw) * BB + b0 + lane] = (_Float16)v;
            partial += v;
        }
    }
    ps[sub][lane] = partial;
    __syncthreads();
    if (sub == 0)
        atomicAdd(&Z[m * BB + b0 + lane],
                  ps[0][lane] + ps[1][lane] + ps[2][lane] + ps[3][lane]);
}

// ---------------------------------------------------------------------------
// Accumulate v3: round-0 owner-computes structure (thread t owns batch
// column b=t, plain LDS add, ZERO atomics) with the occupancy fixed:
//   - u-tile narrowed 64 -> 16 slots: LDS acc 16 KB -> 8 blocks/CU
//     (32 waves, 100% cap) vs round-0's 2 blocks at 64 KB.
//   - 4096 blocks x ~37 entries each (was 1024 x ~147).
//   - hand-pipelined 8-deep entry loop: 8 uniform scalar sorted loads ->
//     8 independent 2B ET loads in flight -> 8 FMA + LDS add.
//   - swizzle t ^ 2*ul: inner writes conflict-free, drain reads 2-way (free).
// Full slot coverage -> no output memset.
// ---------------------------------------------------------------------------
__global__ __launch_bounds__(256, 8) void accumulate3_kernel(
    const _Float16* __restrict__ ET, const int* __restrict__ sorted,
    const int* __restrict__ off, const float* __restrict__ Z,
    const float* __restrict__ weights, float* __restrict__ out)
{
    const int k = blockIdx.x;             // u-tile
    const int t = threadIdx.x;            // b

    __shared__ float acc[TILE * 256];
    #pragma unroll
    for (int i = 0; i < TILE; ++i) acc[i * 256 + t] = 0.0f;
    const float w0 = weights[0] / Z[0 * BB + t];
    const float w1 = weights[1] / Z[1 * BB + t];
    const float w2 = weights[2] / Z[2 * BB + t];
    __syncthreads();

    const int s = off[k], e = off[k + 1];
    int i = s;
    for (; i + 8 <= e; i += 8) {
        int p[8];
        #pragma unroll
        for (int z = 0; z < 8; ++z) p[z] = sorted[i + z];   // uniform -> s_load
        float ev[8];
        #pragma unroll
        for (int z = 0; z < 8; ++z) {
            const int eoff = ((((p[z] >> 6) & 3) * VV + (p[z] >> 8)) << 8);
            ev[z] = (float)ET[eoff + t];                    // 8 loads in flight
        }
        #pragma unroll
        for (int z = 0; z < 8; ++z) {
            const int ul = p[z] & 15;
            const int m  = (p[z] >> 6) & 3;
            const float w = (m == 0) ? w0 : (m == 1) ? w1 : w2;
            acc[ul * 256 + (t ^ (2 * ul))] += w * ev[z];
        }
    }
    for (; i < e; ++i) {
        const int p = sorted[i];
        const int ul = p & 15;
        const int m  = (p >> 6) & 3;
        const int eoff = (((m * VV) + (p >> 8)) << 8);
        const float w = (m == 0) ? w0 : (m == 1) ? w1 : w2;
        acc[ul * 256 + (t ^ (2 * ul))] += w * (float)ET[eoff + t];
    }
    __syncthreads();

    const int u0   = k * TILE;
    const int slot = t & 15;
    const int q    = t >> 4;
    #pragma unroll
    for (int r = 0; r < 16; ++r) {
        const int b = r * 16 + q;
        out[(size_t)b * UU + u0 + slot] = acc[slot * 256 + (b ^ (2 * slot))];
    }
}

// ===========================================================================
// FALLBACK (proven round-2 path) — used only if ws_size < WS_NEED.
// ===========================================================================
#define FB_NBUCK 8
#define FB_BSZ   8192

__global__ __launch_bounds__(256) void fb_count_kernel(
    const int* __restrict__ m0, const int* __restrict__ m1,
    const int* __restrict__ m2, int* __restrict__ cnt)
{
    const int m = blockIdx.y;
    const int* mp = (m == 0) ? m0 : (m == 1) ? m1 : m2;
    __shared__ int hist[FB_NBUCK];
    if (threadIdx.x < FB_NBUCK) hist[threadIdx.x] = 0;
    __syncthreads();
    const int j = blockIdx.x * 256 + threadIdx.x;
    if (j < VV) atomicAdd(&hist[mp[j] >> 13], 1);
    __syncthreads();
    if (threadIdx.x < FB_NBUCK)
        atomicAdd(&cnt[m * FB_NBUCK + threadIdx.x], hist[threadIdx.x]);
}

__global__ void fb_prefix_kernel(const int* __restrict__ cnt,
                                 int* __restrict__ off, int* __restrict__ cursor)
{
    for (int m = 0; m < MM; ++m) {
        int acc = 0;
        for (int k = 0; k < FB_NBUCK; ++k) {
            off[m * (FB_NBUCK + 1) + k] = acc;
            cursor[m * FB_NBUCK + k]    = acc;
            acc += cnt[m * FB_NBUCK + k];
        }
        off[m * (FB_NBUCK + 1) + FB_NBUCK] = acc;
    }
}

__global__ __launch_bounds__(256) void fb_scatter_kernel(
    const int* __restrict__ m0, const int* __restrict__ m1,
    const int* __restrict__ m2, int* __restrict__ cursor,
    int* __restrict__ sorted)
{
    const int m = blockIdx.y;
    const int* mp = (m == 0) ? m0 : (m == 1) ? m1 : m2;
    int* srt = sorted + (size_t)m * VV;
    const int j = blockIdx.x * 256 + threadIdx.x;
    int u = 0, bucket = FB_NBUCK;
    if (j < VV) { u = mp[j]; bucket = u >> 13; }
    const int lane = threadIdx.x & 63;
    const unsigned long long lt = (1ull << lane) - 1ull;
    #pragma unroll
    for (int k = 0; k < FB_NBUCK; ++k) {
        unsigned long long mask = __ballot(bucket == k);
        if (mask) {
            int leader = __ffsll((long long)mask) - 1;
            int base = 0;
            if (lane == leader)
                base = atomicAdd(&cursor[m * FB_NBUCK + k], __popcll(mask));
            base = __shfl(base, leader, 64);
            if (bucket == k) {
                int pos = base + __popcll(mask & lt);
                srt[pos] = ((u & (FB_BSZ - 1)) << 16) | j;
            }
        }
    }
}

__global__ __launch_bounds__(512) void fb_accumulate_kernel(
    const float* __restrict__ l0, const float* __restrict__ l1,
    const float* __restrict__ l2,
    const int* __restrict__ sorted, const int* __restrict__ off,
    const float* __restrict__ winv, float* __restrict__ out)
{
    const int k = blockIdx.x;
    const int b = blockIdx.y;
    __shared__ float acc[FB_BSZ];
    for (int i = threadIdx.x; i < FB_BSZ; i += 512) acc[i] = 0.0f;
    __syncthreads();
    #pragma unroll
    for (int m = 0; m < MM; ++m) {
        const float* lg = (m == 0) ? l0 : (m == 1) ? l1 : l2;
        const float* row = lg + (size_t)b * VV;
        const int* srt = sorted + (size_t)m * VV;
        const float wv = winv[m * BB + b];
        const int s = off[m * (FB_NBUCK + 1) + k];
        const int e = off[m * (FB_NBUCK + 1) + k + 1];
        for (int i = s + threadIdx.x; i < e; i += 512) {
            const int pack = srt[i];
            atomicAdd(&acc[pack >> 16], wv * __expf(row[pack & 0xFFFF]));
        }
    }
    __syncthreads();
    float* orow = out + (size_t)b * UU + (size_t)k * FB_BSZ;
    for (int i = threadIdx.x; i < FB_BSZ; i += 512) orow[i] = acc[i];
}

// ---------------------------------------------------------------------------
extern "C" void kernel_launch(void* const* d_in, const int* in_sizes, int n_in,
                              void* d_out, int out_size, void* d_ws, size_t ws_size,
                              hipStream_t stream)
{
    const float* l0 = (const float*)d_in[0];
    const float* l1 = (const float*)d_in[1];
    const float* l2 = (const float*)d_in[2];
    const int*   m0 = (const int*)d_in[3];
    const int*   m1 = (const int*)d_in[4];
    const int*   m2 = (const int*)d_in[5];
    const float* w  = (const float*)d_in[6];
    float* out = (float*)d_out;
    char* ws = (char*)d_ws;

    if (ws_size >= WS_NEED) {
        float*    Z      = (float*)   (ws + WS_Z);
        int*      hist   = (int*)     (ws + WS_HIST);
        int*      off    = (int*)     (ws + WS_OFF);
        int*      cursor = (int*)     (ws + WS_CURSOR);
        int*      sorted = (int*)     (ws + WS_SORTED);
        _Float16* ET     = (_Float16*)(ws + WS_ET);

        // zero Z (3072 B) + hist (16384 B) in one shot
        hipMemsetAsync(ws, 0, WS_OFF, stream);

        hist_count_kernel<<<256, 256, 0, stream>>>(m0, m1, m2, hist);
        prefix_kernel<<<1, 1024, 0, stream>>>(hist, off, cursor);
        sort_kernel<<<256, 256, 0, stream>>>(m0, m1, m2, cursor, sorted);

        dim3 gtr((VV + 63) / 64, BB / 64, MM);      // (786, 4, 3)
        transpose_exp_kernel<<<gtr, 256, 0, stream>>>(l0, l1, l2, ET, Z);

        accumulate3_kernel<<<NT, 256, 0, stream>>>(ET, sorted, off, Z, w, out);
    } else {
        // round-2 fallback layout
        float* winv   = (float*)(ws + 0);
        int*   cnt    = (int*)  (ws + 3072);
        int*   off    = (int*)  (ws + 3200);
        int*   cursor = (int*)  (ws + 3456);
        int*   sorted = (int*)  (ws + 3584);

        hipMemsetAsync(cnt, 0, MM * FB_NBUCK * sizeof(int), stream);
        row_sums_kernel<<<MM * BB, 512, 0, stream>>>(l0, l1, l2, w, winv);
        dim3 gmap((VV + 255) / 256, MM);
        fb_count_kernel<<<gmap, 256, 0, stream>>>(m0, m1, m2, cnt);
        fb_prefix_kernel<<<1, 1, 0, stream>>>(cnt, off, cursor);
        fb_scatter_kernel<<<gmap, 256, 0, stream>>>(m0, m1, m2, cursor, sorted);
        dim3 gacc(FB_NBUCK, BB);
        fb_accumulate_kernel<<<gacc, 512, 0, stream>>>(l0, l1, l2, sorted, off, winv, out);
    }
}